// Round 2
// baseline (239.131 us; speedup 1.0000x reference)
//
#include <hip/hip_runtime.h>

#define BATCH 16
#define INCH  64
#define IMH   128
#define IMW   128
#define OUTCH 128
#define SUB   8
#define OH    126
#define OW    126

// spatial tile per block
#define YT 4
#define XT 16
#define TR (YT + 2)        // 6 input rows
#define RS 20              // LDS row stride (floats); 18 used + 2 pad
#define CHS (TR * RS)      // 120 floats per channel
#define LDS_FLOATS (INCH * CHS)          // 7680
#define LDS_VEC4   (LDS_FLOATS / 4)      // 1920

#define GLOAD_LDS(g, l) __builtin_amdgcn_global_load_lds( \
    (const __attribute__((address_space(1))) void*)(g),   \
    (__attribute__((address_space(3))) void*)(l), 16, 0, 0)

// ---- weight prep: repack into [s][p] chunks of 20 floats (16B aligned) ----
// chunk c = s*64+p:  t0..8 = W[o=p][s][.][.],  t9..17 = W[o=p+64][s][.][.]
__global__ __launch_bounds__(256)
void prep_weights_kernel(const float* __restrict__ Wg, float* __restrict__ Wp) {
    int idx = blockIdx.x * 256 + threadIdx.x;
    if (idx < 512 * 18) {
        int chunk = idx / 18;
        int t     = idx - chunk * 18;
        int s = chunk >> 6;
        int p = chunk & 63;
        int o  = (t < 9) ? p : p + 64;
        int tt = (t < 9) ? t : t - 9;
        Wp[chunk * 20 + t] = Wg[(o * SUB + s) * 9 + tt];
    }
}

__global__ __launch_bounds__(256, 5)
void Group_Conv_84731114815961_kernel(const float* __restrict__ X,
                                      const float* __restrict__ Wg,
                                      const float* __restrict__ Bias,
                                      const float* __restrict__ Wp,
                                      float* __restrict__ Out) {
    __shared__ float xin[LDS_FLOATS];   // 30720 B -> 5 blocks/CU

    // bijective XCD swizzle: 4096 blocks, 8 XCDs, 512 consecutive work-ids/XCD
    const int bid = blockIdx.x;
    const int wg  = (bid & 7) * 512 + (bid >> 3);
    const int tx  = wg & 7;          // x tile   (fastest in work order)
    const int ty  = (wg >> 3) & 31;  // y tile
    const int b   = wg >> 8;         // batch
    const int x0  = tx * XT;
    const int y0  = ty * YT;
    const int tid = threadIdx.x;

    // ---- stage 64ch x 6 rows x 20 cols via global_load_lds (linear dest) ----
    const float* Xb = X + (size_t)b * INCH * IMH * IMW;
    #pragma unroll
    for (int it = 0; it < 8; ++it) {
        int k = it * 256 + tid;
        if (k < LDS_VEC4) {               // it==7: tid<128, wave-uniform halves
            int c   = k / 30;             // 30 float4 per channel
            int rem = k - c * 30;
            int r   = rem / 5;
            int col = (rem - r * 5) * 4;  // 0,4,8,12,16
            int sr = y0 + r;   if (sr > IMH - 1) sr = IMH - 1;
            int sc = x0 + col; if (sc > IMW - 4) sc = IMW - 4;
            GLOAD_LDS(Xb + (c * IMH + sr) * IMW + sc, &xin[k * 4]);
        }
    }
    __syncthreads();

    const int p  = tid >> 2;   // o-pair 0..63  (o = p, p+64)
    const int xg = tid & 3;    // 4-col group
    const int cb = xg << 2;

    float acc0[YT][4];
    float acc1[YT][4];
    #pragma unroll
    for (int y = 0; y < YT; ++y)
        #pragma unroll
        for (int q = 0; q < 4; ++q) { acc0[y][q] = 0.f; acc1[y][q] = 0.f; }

    const bool useWp = (Wp != nullptr);

    for (int s = 0; s < SUB; ++s) {
        const int c = (p + s) & 63;
        float w0[9], w1[9];
        if (useWp) {
            const float4* wc = reinterpret_cast<const float4*>(Wp + ((s << 6) + p) * 20);
            const float4 f0 = wc[0], f1 = wc[1], f2 = wc[2], f3 = wc[3], f4 = wc[4];
            w0[0]=f0.x; w0[1]=f0.y; w0[2]=f0.z; w0[3]=f0.w;
            w0[4]=f1.x; w0[5]=f1.y; w0[6]=f1.z; w0[7]=f1.w;
            w0[8]=f2.x;
            w1[0]=f2.y; w1[1]=f2.z; w1[2]=f2.w;
            w1[3]=f3.x; w1[4]=f3.y; w1[5]=f3.z; w1[6]=f3.w;
            w1[7]=f4.x; w1[8]=f4.y;
        } else {
            const float* w0p = Wg + (p * SUB + s) * 9;
            const float* w1p = Wg + ((p + 64) * SUB + s) * 9;
            #pragma unroll
            for (int t = 0; t < 9; ++t) { w0[t] = w0p[t]; w1[t] = w1p[t]; }
        }

        const float* base = &xin[c * CHS + cb];
        #pragma unroll
        for (int r = 0; r < TR; ++r) {
            const float4 a  = *reinterpret_cast<const float4*>(base + r * RS);
            const float2 b2 = *reinterpret_cast<const float2*>(base + r * RS + 4);
            float v[6];
            v[0] = a.x; v[1] = a.y; v[2] = a.z; v[3] = a.w; v[4] = b2.x; v[5] = b2.y;
            #pragma unroll
            for (int i = 0; i < 3; ++i) {
                const int yo = r - i;
                if (yo >= 0 && yo < YT) {
                    #pragma unroll
                    for (int j = 0; j < 3; ++j) {
                        const float ww0 = w0[i * 3 + j];
                        const float ww1 = w1[i * 3 + j];
                        #pragma unroll
                        for (int q = 0; q < 4; ++q) {
                            acc0[yo][q] = fmaf(v[q + j], ww0, acc0[yo][q]);
                            acc1[yo][q] = fmaf(v[q + j], ww1, acc1[yo][q]);
                        }
                    }
                }
            }
        }
    }

    // ---- epilogue: bias + masked stores ----
    const float bz0 = Bias[p];
    const float bz1 = Bias[p + 64];
    const int   xcol = x0 + cb;
    float* O0 = Out + (((size_t)b * OUTCH + p)      * OH) * OW;
    float* O1 = Out + (((size_t)b * OUTCH + p + 64) * OH) * OW;

    #pragma unroll
    for (int y = 0; y < YT; ++y) {
        const int oy = y0 + y;
        if (oy < OH) {
            float* o0 = O0 + oy * OW + xcol;
            float* o1 = O1 + oy * OW + xcol;
            if (xcol + 3 < OW) {
                float4 s0, s1;
                s0.x = acc0[y][0] + bz0; s0.y = acc0[y][1] + bz0;
                s0.z = acc0[y][2] + bz0; s0.w = acc0[y][3] + bz0;
                s1.x = acc1[y][0] + bz1; s1.y = acc1[y][1] + bz1;
                s1.z = acc1[y][2] + bz1; s1.w = acc1[y][3] + bz1;
                *reinterpret_cast<float4*>(o0) = s0;
                *reinterpret_cast<float4*>(o1) = s1;
            } else {
                #pragma unroll
                for (int q = 0; q < 4; ++q) {
                    if (xcol + q < OW) {
                        o0[q] = acc0[y][q] + bz0;
                        o1[q] = acc1[y][q] + bz1;
                    }
                }
            }
        }
    }
}

extern "C" void kernel_launch(void* const* d_in, const int* in_sizes, int n_in,
                              void* d_out, int out_size, void* d_ws, size_t ws_size,
                              hipStream_t stream) {
    const float* X    = (const float*)d_in[0];
    const float* Wg   = (const float*)d_in[1];
    const float* Bias = (const float*)d_in[2];
    float*       Out  = (float*)d_out;

    float* Wp = nullptr;
    if (d_ws && ws_size >= 512 * 20 * sizeof(float)) {
        Wp = (float*)d_ws;
        prep_weights_kernel<<<36, 256, 0, stream>>>(Wg, Wp);
    }

    // 8 x-tiles * 32 y-tiles * 16 batches = 4096 blocks (1-D, XCD-swizzled)
    Group_Conv_84731114815961_kernel<<<4096, 256, 0, stream>>>(X, Wg, Bias, Wp, Out);
}

// Round 3
// 162.637 us; speedup vs baseline: 1.4703x; 1.4703x over previous
//
#include <hip/hip_runtime.h>

#define SUB   8
#define INCH  64
#define IMH   128
#define IMW   128
#define OUTCH 128
#define OH    126
#define OW    126

#define YT 8            // output rows per block
#define XT 16           // output cols per block
#define TR 10           // input rows staged (YT+2)
#define RS 20           // words per staged row (18 used + 2 pad)
#define NCH 39          // channels staged (32 owned + 7 halo)
#define CHS 204         // words per channel (10*20=200 + 4 pad; 204%32=12 -> bank phase spread)
#define LDS_WORDS (NCH * CHS)      // 7956
#define LDS_VEC4  ((LDS_WORDS)/4)  // 1989
#define TRB 6           // input rows per y-half (4 out rows + 2)

// ---- weight prep: chunk c = s*64 + o0 (o0 in [0,64)): 20 floats, 16B aligned
//      t0..8  = W[o0][s][.][.],  t9..17 = W[o0+64][s][.][.]
__global__ __launch_bounds__(256)
void prep_weights_kernel(const float* __restrict__ Wg, float* __restrict__ Wp) {
    int idx = blockIdx.x * 256 + threadIdx.x;
    if (idx < 512 * 18) {
        int chunk = idx / 18;
        int t     = idx - chunk * 18;
        int s = chunk >> 6;
        int p = chunk & 63;
        int o  = (t < 9) ? p : p + 64;
        int tt = (t < 9) ? t : t - 9;
        Wp[chunk * 20 + t] = Wg[(o * SUB + s) * 9 + tt];
    }
}

__global__ __launch_bounds__(256, 5)
void Group_Conv_84731114815961_kernel(const float* __restrict__ X,
                                      const float* __restrict__ Wg,
                                      const float* __restrict__ Bias,
                                      const float* __restrict__ Wp,
                                      float* __restrict__ Out) {
    __shared__ float xin[LDS_WORDS];   // 31824 B -> 5 blocks/CU

    const int tx = blockIdx.x;        // 0..7  (fastest in dispatch, like round 1)
    const int ty = blockIdx.y;        // 0..15
    const int h  = blockIdx.z & 1;    // channel half
    const int b  = blockIdx.z >> 1;   // batch
    const int x0 = tx * XT;
    const int y0 = ty * YT;
    const int tid = threadIdx.x;

    // ---- stage NCH channels x 10 rows x 20 cols (VGPR float4 path) ----
    const float* Xb = X + (size_t)b * INCH * IMH * IMW;
    #pragma unroll
    for (int it = 0; it < 8; ++it) {
        int k = it * 256 + tid;
        if (k < LDS_VEC4) {
            int cl  = k / 51;                 // 51 float4 per channel (204 words)
            int rem = k - cl * 51;
            int r   = rem / 5;                // 0..10 (10 = pad slot)
            int col = (rem - r * 5) * 4;      // 0,4,8,12,16 (rem==50 -> r=10,col=0)
            int cg  = (h * 32 + cl) & 63;
            int sr = y0 + r;   if (sr > IMH - 1) sr = IMH - 1;
            int sc = x0 + col; if (sc > IMW - 4) sc = IMW - 4;
            const float4 v = *reinterpret_cast<const float4*>(Xb + (cg * IMH + sr) * IMW + sc);
            *reinterpret_cast<float4*>(&xin[k * 4]) = v;
        }
    }
    __syncthreads();

    const int p  = tid >> 3;          // 0..31  o-pair within half
    const int yh = (tid >> 2) & 1;    // y half (rows 4yh..4yh+3)
    const int xg = tid & 3;           // 4-col group
    const int cb = xg << 2;
    const int o0 = h * 32 + p;        // o1 = o0 + 64

    float acc0[4][4];
    float acc1[4][4];
    #pragma unroll
    for (int y = 0; y < 4; ++y)
        #pragma unroll
        for (int q = 0; q < 4; ++q) { acc0[y][q] = 0.f; acc1[y][q] = 0.f; }

    const bool useWp = (Wp != nullptr);

    for (int s = 0; s < SUB; ++s) {
        const int cl = p + s;         // 0..38 staged channel index
        float w0[9], w1[9];
        if (useWp) {
            const float4* wc = reinterpret_cast<const float4*>(Wp + ((s << 6) + o0) * 20);
            const float4 f0 = wc[0], f1 = wc[1], f2 = wc[2], f3 = wc[3], f4 = wc[4];
            w0[0]=f0.x; w0[1]=f0.y; w0[2]=f0.z; w0[3]=f0.w;
            w0[4]=f1.x; w0[5]=f1.y; w0[6]=f1.z; w0[7]=f1.w;
            w0[8]=f2.x;
            w1[0]=f2.y; w1[1]=f2.z; w1[2]=f2.w;
            w1[3]=f3.x; w1[4]=f3.y; w1[5]=f3.z; w1[6]=f3.w;
            w1[7]=f4.x; w1[8]=f4.y;
        } else {
            const float* w0p = Wg + (o0 * SUB + s) * 9;
            const float* w1p = Wg + ((o0 + 64) * SUB + s) * 9;
            #pragma unroll
            for (int t = 0; t < 9; ++t) { w0[t] = w0p[t]; w1[t] = w1p[t]; }
        }

        const float* base = &xin[cl * CHS + (yh << 2) * RS + cb];
        #pragma unroll
        for (int r = 0; r < TRB; ++r) {
            const float4 a  = *reinterpret_cast<const float4*>(base + r * RS);
            const float2 b2 = *reinterpret_cast<const float2*>(base + r * RS + 4);
            float v[6];
            v[0] = a.x; v[1] = a.y; v[2] = a.z; v[3] = a.w; v[4] = b2.x; v[5] = b2.y;
            #pragma unroll
            for (int i = 0; i < 3; ++i) {
                const int yo = r - i;
                if (yo >= 0 && yo < 4) {
                    #pragma unroll
                    for (int j = 0; j < 3; ++j) {
                        const float ww0 = w0[i * 3 + j];
                        const float ww1 = w1[i * 3 + j];
                        #pragma unroll
                        for (int q = 0; q < 4; ++q) {
                            acc0[yo][q] = fmaf(v[q + j], ww0, acc0[yo][q]);
                            acc1[yo][q] = fmaf(v[q + j], ww1, acc1[yo][q]);
                        }
                    }
                }
            }
        }
    }

    // ---- epilogue: bias + masked stores ----
    const float bz0 = Bias[o0];
    const float bz1 = Bias[o0 + 64];
    const int   xcol = x0 + cb;
    const int   yb   = y0 + (yh << 2);
    float* O0 = Out + (((size_t)b * OUTCH + o0)      * OH) * OW;
    float* O1 = Out + (((size_t)b * OUTCH + o0 + 64) * OH) * OW;

    #pragma unroll
    for (int y = 0; y < 4; ++y) {
        const int oy = yb + y;
        if (oy < OH) {
            float* o0p = O0 + oy * OW + xcol;
            float* o1p = O1 + oy * OW + xcol;
            if (xcol + 3 < OW) {
                float4 s0, s1;
                s0.x = acc0[y][0] + bz0; s0.y = acc0[y][1] + bz0;
                s0.z = acc0[y][2] + bz0; s0.w = acc0[y][3] + bz0;
                s1.x = acc1[y][0] + bz1; s1.y = acc1[y][1] + bz1;
                s1.z = acc1[y][2] + bz1; s1.w = acc1[y][3] + bz1;
                *reinterpret_cast<float4*>(o0p) = s0;
                *reinterpret_cast<float4*>(o1p) = s1;
            } else {
                #pragma unroll
                for (int q = 0; q < 4; ++q) {
                    if (xcol + q < OW) {
                        o0p[q] = acc0[y][q] + bz0;
                        o1p[q] = acc1[y][q] + bz1;
                    }
                }
            }
        }
    }
}

extern "C" void kernel_launch(void* const* d_in, const int* in_sizes, int n_in,
                              void* d_out, int out_size, void* d_ws, size_t ws_size,
                              hipStream_t stream) {
    const float* X    = (const float*)d_in[0];
    const float* Wg   = (const float*)d_in[1];
    const float* Bias = (const float*)d_in[2];
    float*       Out  = (float*)d_out;

    float* Wp = nullptr;
    if (d_ws && ws_size >= 512 * 20 * sizeof(float)) {
        Wp = (float*)d_ws;
        prep_weights_kernel<<<36, 256, 0, stream>>>(Wg, Wp);
    }

    // native 3-D grid, tx fastest (round-1 order that gave WRITE ~177 MB)
    dim3 grid(8, 16, 32);   // x-tiles, y-tiles, (batch x channel-half)
    Group_Conv_84731114815961_kernel<<<grid, 256, 0, stream>>>(X, Wg, Bias, Wp, Out);
}